// Round 24
// baseline (102.745 us; speedup 1.0000x reference)
//
#include <hip/hip_runtime.h>

// Fused causal attention block: qkv = x@Wqkv -> flash-attn -> out = o@Wout
// B=2, S=2048, D=1024, H=16, hd=64. All matmuls in bf16 MFMA (fp32 accum).
//   prep_kernel  : weight transposes only (x cvt fused into gemm_qkv)
//   gemm_qkv     : 128x128/BK=64, 8 waves, XCD-chunked; A read fp32 from x,
//                  converted in-register (cvt_pk RNE) and ds_written to LDS
//   attn_kernel  : 4 waves/block, 4-way kv split, backfill (proven v6)
//   gemm_bt64    : 64x128 out-projection (2 blk/CU occupancy fix)

typedef unsigned short u16;
typedef unsigned int   u32;
typedef __attribute__((ext_vector_type(4))) u16    u16x4;
typedef __attribute__((ext_vector_type(8))) u16    u16x8;
typedef __attribute__((ext_vector_type(4))) u32    u32x4;
typedef __attribute__((ext_vector_type(4))) short  s16x4;
typedef __attribute__((ext_vector_type(8))) __bf16 bf16x8;
typedef __attribute__((ext_vector_type(4))) float  f32x4;
typedef __attribute__((ext_vector_type(16))) float f32x16;

#define DEV static __device__ __forceinline__

DEV u16 f2b(float f) {             // fp32 -> bf16, round-to-nearest-even
  unsigned u = __float_as_uint(f);
  u += 0x7fffu + ((u >> 16) & 1u);
  return (u16)(u >> 16);
}

DEV void gload_lds16(const void* g, void* l) {
  __builtin_amdgcn_global_load_lds((const __attribute__((address_space(1))) void*)g,
                                   (__attribute__((address_space(3))) void*)l, 16, 0, 0);
}

DEV unsigned lds_off(const void* p) {
  return (unsigned)(unsigned long long)(const __attribute__((address_space(3))) void*)p;
}

// ds_read_b64_tr_b16: lane's byte addr A selects column (A>>3)&15 of the
// 128B-aligned 4x16 bf16 subtile containing A; returns elems col+16j, j=0..3.
DEV s16x4 tr_read(unsigned off) {
  s16x4 d;
  asm volatile("ds_read_b64_tr_b16 %0, %1" : "=v"(d) : "v"(off));
  return d;
}

DEV u32 cvt_pk(float lo, float hi) {   // packed {bf16(lo), bf16(hi)}, RNE
  u32 r;
  asm("v_cvt_pk_bf16_f32 %0, %1, %2" : "=v"(r) : "v"(lo), "v"(hi));
  return r;
}

// v_permlane32_swap_b32: x <- [x.lo31 | y.lo31], y <- [x.hi31 | y.hi31]
DEV void pswap(u32& x, u32& y) {
  asm volatile("v_permlane32_swap_b32 %0, %1" : "+v"(x), "+v"(y));
}

DEV f32x4 mfma32(bf16x8 a, bf16x8 b, f32x4 c) {
  return __builtin_amdgcn_mfma_f32_16x16x32_bf16(a, b, c, 0, 0, 0);
}
DEV f32x16 mfma3232(bf16x8 a, bf16x8 b, f32x16 c) {
  return __builtin_amdgcn_mfma_f32_32x32x16_bf16(a, b, c, 0, 0, 0);
}

// ------- prep: weight transposes only. blocks 0..3071: w_qkv^T (scaled
// first 1024 cols = W_q by 0.125*log2e); 3072..4095: w_out^T. -------
__global__ __launch_bounds__(256) void prep_kernel(const float* __restrict__ w_qkv,
                                                   u16* __restrict__ wqkvT,
                                                   const float* __restrict__ w_out,
                                                   u16* __restrict__ woutT) {
  __shared__ u16 ls[32][33];
  const int bid = (int)blockIdx.x;
  const int t = threadIdx.x;
  const float* w; u16* wt; int Ndim, tn, tk; float s;
  if (bid < 3072) {                       // ---- w_qkv [1024][3072] -> [3072][1024]
    w = w_qkv; wt = wqkvT; Ndim = 3072;
    tn = (bid % 96) * 32; tk = (bid / 96) * 32;
    s = (tn < 1024) ? 0.18033688011112042f : 1.0f;   // scale W_q
  } else {                                // ---- w_out [1024][1024] -> [1024][1024]
    const int q = bid - 3072;
    w = w_out; wt = woutT; Ndim = 1024;
    tn = (q % 32) * 32; tk = (q / 32) * 32;
    s = 1.0f;
  }
  const int r = t >> 3, c4 = (t & 7) * 4;
  const float4 v = *(const float4*)(w + (size_t)(tk + r) * Ndim + tn + c4);
  ls[r][c4 + 0] = f2b(v.x * s); ls[r][c4 + 1] = f2b(v.y * s);
  ls[r][c4 + 2] = f2b(v.z * s); ls[r][c4 + 3] = f2b(v.w * s);
  __syncthreads();
  u16x4 ov = { ls[c4 + 0][r], ls[c4 + 1][r], ls[c4 + 2][r], ls[c4 + 3][r] };
  *(u16x4*)(wt + (size_t)(tn + r) * 1024 + tk + c4) = ov;
}

// ------- qkv GEMM: C[4096,3072](bf16) = x[4096,1024](f32) @ Bt^T -------
// 128x128 tile, BK=64, XCD-chunked swizzle, 8 waves (2M x 4N, wave 64x32).
// A is read DIRECTLY from fp32 x (saves the prep cvt's 24MB HBM round-trip):
// 2x float4 per chunk -> v_cvt_pk_bf16_f32 (RNE, == f2b) -> ds_write_b128 to
// the same swizzled LDS offsets. B staged via global_load_lds as before.
// All stores/DMAs drain at the existing __syncthreads.
__global__ __launch_bounds__(512, 2) void gemm_qkv(const float* __restrict__ X,
                                                   const u16* __restrict__ Bt,
                                                   u16* __restrict__ C, const int ldc) {
  const int gx = gridDim.x;
  const int id = (int)(blockIdx.y * gx + blockIdx.x);
  const int nxp = gx >> 3;                 // N-tiles per XCD chunk
  const int xcd = id & 7, loc = id >> 3;   // HW: XCD = id % 8 round-robin
  const int tn = (xcd * nxp + loc % nxp) * 128;
  const int tm = (loc / nxp) * 128;
  const int tid = (int)threadIdx.x;
  const int lane = tid & 63, wid = tid >> 6;
  const int wm = wid >> 2, wn = wid & 3;   // 2M x 4N waves
  const int lg = lane >> 4, lc = lane & 15;
  __shared__ __align__(128) u16 lsA[128 * 64];   // 16KB
  __shared__ __align__(128) u16 lsB[128 * 64];   // 16KB

  f32x4 acc[4][2];
#pragma unroll
  for (int i = 0; i < 4; ++i)
#pragma unroll
    for (int j = 0; j < 2; ++j) acc[i][j] = (f32x4){0.f, 0.f, 0.f, 0.f};

  // t-independent chunk maps (chunk p: row=p>>3, src chunk cg=(p&7)^(row&7))
  unsigned asrc[2], bsrc[2], ldst[2];
#pragma unroll
  for (int c = 0; c < 2; ++c) {
    const int p = tid + c * 512;
    const int row = p >> 3;
    const int cg = (p & 7) ^ (row & 7);
    asrc[c] = (unsigned)((tm + row) * 1024 + cg * 8);
    bsrc[c] = (unsigned)((tn + row) * 1024 + cg * 8);
    ldst[c] = (unsigned)(p * 16);
  }

  for (int kt = 0; kt < 16; ++kt) {        // K-step = 64
    const unsigned ko = (unsigned)(kt * 64);
    f32x4 a0[2], a1[2];
#pragma unroll
    for (int c = 0; c < 2; ++c) {          // issue all loads first
      const float* ap = X + asrc[c] + ko;
      a0[c] = *(const f32x4*)ap;
      a1[c] = *(const f32x4*)(ap + 4);
      gload_lds16(Bt + bsrc[c] + ko, (char*)lsB + ldst[c]);
    }
#pragma unroll
    for (int c = 0; c < 2; ++c) {          // convert + LDS write (RNE == f2b)
      u32x4 w;
      w[0] = cvt_pk(a0[c][0], a0[c][1]);
      w[1] = cvt_pk(a0[c][2], a0[c][3]);
      w[2] = cvt_pk(a1[c][0], a1[c][1]);
      w[3] = cvt_pk(a1[c][2], a1[c][3]);
      *(u32x4*)((char*)lsA + ldst[c]) = w;
    }
    __syncthreads();                       // drains ds_writes + B DMAs
#pragma unroll
    for (int kk = 0; kk < 2; ++kk) {       // two K=32 slices per K-step
      bf16x8 af[4], bg[2];
#pragma unroll
      for (int i = 0; i < 4; ++i) {
        const int ar = wm * 64 + i * 16 + lc;
        af[i] = *(const bf16x8*)(lsA + ar * 64 + ((kk * 4 + lg) ^ (ar & 7)) * 8);
      }
#pragma unroll
      for (int j = 0; j < 2; ++j) {
        const int br = wn * 32 + j * 16 + lc;
        bg[j] = *(const bf16x8*)(lsB + br * 64 + ((kk * 4 + lg) ^ (br & 7)) * 8);
      }
#pragma unroll
      for (int i = 0; i < 4; ++i)
#pragma unroll
        for (int j = 0; j < 2; ++j)
          acc[i][j] = mfma32(af[i], bg[j], acc[i][j]);
    }
    __syncthreads();
  }

#pragma unroll
  for (int i = 0; i < 4; ++i) {
#pragma unroll
    for (int r = 0; r < 4; ++r) {
      const int m = tm + wm * 64 + i * 16 + lg * 4 + r;   // C/D: row=(l>>4)*4+r
#pragma unroll
      for (int j = 0; j < 2; ++j) {
        const int n = tn + wn * 32 + j * 16 + lc;          // C/D: col=l&15
        C[(size_t)m * ldc + n] = f2b(acc[i][j][r]);
      }
    }
  }
}

// ------- 64x128-tile fp32-out GEMM for the out projection (occupancy fix) ---
__global__ __launch_bounds__(256) void gemm_bt64(const u16* __restrict__ A,
                                                 const u16* __restrict__ Bt,
                                                 float* __restrict__ C, const int ldc) {
  const int id = (int)(blockIdx.y * 8 + blockIdx.x);
  const int tn = (id & 7) * 128;
  const int tm = (id >> 3) * 64;
  const int tid = threadIdx.x;
  const int wave = tid >> 6, lane = tid & 63;
  const int wc = wave;                      // 4 waves = 4 n-quadrants of 32
  const int lg = lane >> 4, lc = lane & 15;
  __shared__ __align__(128) u16 lsA[64 * 32];    // 4KB
  __shared__ __align__(128) u16 lsB[128 * 32];   // 8KB

  f32x4 acc[4][2];
#pragma unroll
  for (int i = 0; i < 4; ++i)
#pragma unroll
    for (int j = 0; j < 2; ++j) acc[i][j] = (f32x4){0.f, 0.f, 0.f, 0.f};

  for (int kt = 0; kt < 32; ++kt) {
    {   // A: 256 chunks, 1 per thread
      const int p = tid;
      const int row = p >> 2, ck = p & 3;
      const int cg = ck ^ ((row >> 1) & 3);
      gload_lds16(A + (size_t)(tm + row) * 1024 + kt * 32 + cg * 8, (char*)lsA + p * 16);
    }
#pragma unroll
    for (int c = 0; c < 2; ++c) {   // B: 512 chunks, 2 per thread
      const int p = tid + c * 256;
      const int row = p >> 2, ck = p & 3;
      const int cg = ck ^ ((row >> 1) & 3);
      gload_lds16(Bt + (size_t)(tn + row) * 1024 + kt * 32 + cg * 8, (char*)lsB + p * 16);
    }
    __syncthreads();
    bf16x8 af[4], bg[2];
#pragma unroll
    for (int i = 0; i < 4; ++i) {
      const int ar = i * 16 + lc;
      af[i] = *(const bf16x8*)(lsA + ar * 32 + (lg ^ ((ar >> 1) & 3)) * 8);
    }
#pragma unroll
    for (int j = 0; j < 2; ++j) {
      const int br = wc * 32 + j * 16 + lc;
      bg[j] = *(const bf16x8*)(lsB + br * 32 + (lg ^ ((br >> 1) & 3)) * 8);
    }
#pragma unroll
    for (int i = 0; i < 4; ++i)
#pragma unroll
      for (int j = 0; j < 2; ++j)
        acc[i][j] = mfma32(af[i], bg[j], acc[i][j]);
    __syncthreads();
  }

#pragma unroll
  for (int i = 0; i < 4; ++i) {
#pragma unroll
    for (int r = 0; r < 4; ++r) {
      const int m = tm + i * 16 + lg * 4 + r;            // C/D: row=(l>>4)*4+r
#pragma unroll
      for (int j = 0; j < 2; ++j) {
        const int n = tn + wc * 32 + j * 16 + lc;        // C/D: col=l&15
        C[(size_t)m * ldc + n] = acc[i][j][r];
      }
    }
  }
}

// ------- flash attention v6: 4 waves/block, 4-way kv split, backfill -------
__global__ __launch_bounds__(256, 2) void attn_kernel(const u16* __restrict__ qkv,
                                                      u16* __restrict__ o) {
  const int qb  = 63 - (int)(blockIdx.x >> 5);  // LPT: longest first
  const int bh  = blockIdx.x & 31;
  const int b   = bh >> 4, h = bh & 15;
  const int tid  = threadIdx.x;
  const int wave = tid >> 6, lane = tid & 63;
  const int l31 = lane & 31, lg2 = lane >> 5;

  __shared__ __align__(128) char smem[4][8192];  // per-wave K(4KB)+V(4KB)
  __shared__ float lsm[4][32];
  char* wb = smem[wave];
  const unsigned vb = lds_off(wb + 4096);

  const size_t bS = (size_t)b * 2048;
  const int T  = qb + 1;
  const int q0 = qb * 32;

  const u16* qrow = qkv + (bS + q0 + l31) * 3072 + h * 64;
  bf16x8 qf[4];
#pragma unroll
  for (int m = 0; m < 4; ++m)
    qf[m] = *(const bf16x8*)(qrow + 16 * m + 8 * lg2);

  unsigned koff[4], voff[4];
#pragma unroll
  for (int c = 0; c < 4; ++c) {
    const int p = c * 64 + lane;
    {
      const int row = p >> 3;
      const int cg = (p & 7) ^ (row & 7);
      koff[c] = (unsigned)(row * 3072 + 1024 + h * 64 + cg * 8);
    }
    {
      const int s = p >> 3, cw = p & 7;
      voff[c] = (unsigned)((4 * (s >> 2) + (cw >> 1)) * 3072 + 2048 + h * 64
                           + (s & 3) * 16 + (cw & 1) * 8);
    }
  }

  auto STAGE = [&](int t) {
    const u16* base = qkv + (bS + (size_t)t * 32) * 3072;
#pragma unroll
    for (int c = 0; c < 4; ++c)
      gload_lds16(base + koff[c], wb + (c * 64 + lane) * 16);
#pragma unroll
    for (int c = 0; c < 4; ++c)
      gload_lds16(base + voff[c], wb + 4096 + (c * 64 + lane) * 16);
  };

  float lsum = 0.f;
  f32x16 accO[2];
#pragma unroll
  for (int r = 0; r < 16; ++r) { accO[0][r] = 0.f; accO[1][r] = 0.f; }

  if (wave < T) STAGE(wave);

  for (int t = wave; t < T; t += 4) {
    asm volatile("s_waitcnt vmcnt(0)" ::: "memory");   // own prefetch landed
    __builtin_amdgcn_sched_barrier(0);

    // ---- issue ALL DS reads of tile t up front ----
    const u16* kbp = (const u16*)wb + l31 * 64;
    bf16x8 kf[4];
#pragma unroll
    for (int m = 0; m < 4; ++m)
      kf[m] = *(const bf16x8*)(kbp + (((2 * m + lg2) ^ (l31 & 7)) * 8));
    s16x4 vr[2][2][2];
#pragma unroll
    for (int db = 0; db < 2; ++db)
#pragma unroll
      for (int hh = 0; hh < 2; ++hh) {
        const unsigned a0 = vb +
          (unsigned)(((4 * hh + 2 * lg2) * 4 + db * 2 + (l31 >> 4)) * 128 + (l31 & 15) * 8);
        vr[db][hh][0] = tr_read(a0);
        vr[db][hh][1] = tr_read(a0 + 512);
      }
    asm volatile("s_waitcnt lgkmcnt(0)" ::: "memory");  // buffer fully read out
    __builtin_amdgcn_sched_barrier(0);

    if (t + 4 < T) STAGE(t + 4);               // prefetch spans whole compute
    __builtin_amdgcn_sched_barrier(0);

    // ---- QK^T (A=K rows=kv=l31, B=Q cols=q) -> S[kv][q] ----
    f32x16 sc;
#pragma unroll
    for (int r = 0; r < 16; ++r) sc[r] = 0.f;
    __builtin_amdgcn_s_setprio(1);
#pragma unroll
    for (int m = 0; m < 4; ++m)
      sc = mfma3232(kf[m], qf[m], sc);
    __builtin_amdgcn_s_setprio(0);

    // ---- P = exp2(S) (scale folded into Q; no max-tracking) ----
    float pp[16];
    if (t == T - 1) {                          // diagonal tile: causal mask
#pragma unroll
      for (int r = 0; r < 16; ++r) {
        const int kvp = (r & 3) + 8 * (r >> 2) + 4 * lg2;
        pp[r] = (kvp <= l31) ? exp2f(sc[r]) : 0.f;
      }
    } else {
#pragma unroll
      for (int r = 0; r < 16; ++r) pp[r] = exp2f(sc[r]);
    }
#pragma unroll
    for (int r = 0; r < 16; ++r) lsum += pp[r];

    // ---- in-register P -> A-operand (8 cvt_pk + 4 permlane32_swap) ----
    u32 a01 = cvt_pk(pp[0], pp[1]),   a23 = cvt_pk(pp[2], pp[3]);
    u32 b01 = cvt_pk(pp[4], pp[5]),   b23 = cvt_pk(pp[6], pp[7]);
    u32 c01 = cvt_pk(pp[8], pp[9]),   c23 = cvt_pk(pp[10], pp[11]);
    u32 d01 = cvt_pk(pp[12], pp[13]), d23 = cvt_pk(pp[14], pp[15]);
    pswap(a01, b01); pswap(a23, b23);
    pswap(c01, d01); pswap(c23, d23);
    union Frag { u32 w[4]; bf16x8 v; };
    Frag f0, f1;
    f0.w[0] = a01; f0.w[1] = a23; f0.w[2] = b01; f0.w[3] = b23;
    f1.w[0] = c01; f1.w[1] = c23; f1.w[2] = d01; f1.w[3] = d23;

    // ---- PV: accO[dblk] += P * V ----
    __builtin_amdgcn_s_setprio(1);
#pragma unroll
    for (int db = 0; db < 2; ++db) {
      union { s16x4 hh[2]; bf16x8 v; } u0, u1;
      u0.hh[0] = vr[db][0][0]; u0.hh[1] = vr[db][0][1];
      u1.hh[0] = vr[db][1][0]; u1.hh[1] = vr[db][1][1];
      accO[db] = mfma3232(f0.v, u0.v, accO[db]);
      accO[db] = mfma3232(f1.v, u1.v, accO[db]);
    }
    __builtin_amdgcn_s_setprio(0);
  }

  // ---- merge: pairwise tree. regions A = smem[0], B = smem[2] (8KB each) ----
  lsum += __shfl_xor(lsum, 32);
  if (lane < 32) lsm[wave][l31] = lsum;
  float* mA = (float*)smem[0];                 // [32][64] f32
  float* mB = (float*)smem[2];                 // [32][64] f32
  __syncthreads();                             // all waves done with K/V LDS
  if ((wave & 1) == 0) {                       // w0 -> A, w2 -> B: write
    float* m = (wave == 0) ? mA : mB;
#pragma unroll
    for (int db = 0; db < 2; ++db)
#pragma unroll
      for (int r = 0; r < 16; ++r) {
        const int qp = (r & 3) + 8 * (r >> 2) + 4 * lg2;
        m[qp * 64 + db * 32 + l31] = accO[db][r];
      }
  }
  __syncthreads();
  if ((wave & 1) == 1) {                       // w1 -> A, w3 -> B: accumulate
    float* m = (wave == 1) ? mA : mB;
#pragma unroll
    for (int db = 0; db < 2; ++db)
#pragma unroll
      for (int r = 0; r < 16; ++r) {
        const int qp = (r & 3) + 8 * (r >> 2) + 4 * lg2;
        m[qp * 64 + db * 32 + l31] += accO[db][r];
      }
  }
  __syncthreads();

  // ---- epilogue: 256 threads, row q = tid>>3, cols d0..d0+7 ----
  const int q  = tid >> 3;
  const int d0 = (tid & 7) * 8;
  const float inv = 1.f / (lsm[0][q] + lsm[1][q] + lsm[2][q] + lsm[3][q]);
  u16x8 ov;
#pragma unroll
  for (int e = 0; e < 8; ++e)
    ov[e] = f2b((mA[q * 64 + d0 + e] + mB[q * 64 + d0 + e]) * inv);
  *(u16x8*)(o + (bS + q0 + q) * 1024 + h * 64 + d0) = ov;
}

// ---------------- launch ----------------
extern "C" void kernel_launch(void* const* d_in, const int* in_sizes, int n_in,
                              void* d_out, int out_size, void* d_ws, size_t ws_size,
                              hipStream_t stream) {
  const float* x     = (const float*)d_in[0];
  const float* w_qkv = (const float*)d_in[1];
  const float* w_out = (const float*)d_in[2];
  float* out = (float*)d_out;
  char* ws = (char*)d_ws;

  u16* wqkvT = (u16*)(ws + 8388608);    //  6.0 MB  w_qkv^T bf16 [3072][1024]
  u16* woutT = (u16*)(ws + 14680064);   //  2.0 MB  w_out^T bf16 [1024][1024]
  u16* qkvb  = (u16*)(ws + 16777216);   // 24.0 MB  qkv bf16 [4096][3072]
  u16* ob    = (u16*)(ws + 41943040);   //  8.0 MB  attn out bf16 [4096][1024]

  prep_kernel<<<4096, 256, 0, stream>>>(w_qkv, wqkvT, w_out, woutT);
  gemm_qkv<<<dim3(24, 32), 512, 0, stream>>>(x, wqkvT, qkvb, 3072);
  attn_kernel<<<2048, 256, 0, stream>>>(qkvb, ob);
  gemm_bt64<<<dim3(8, 64), 256, 0, stream>>>(ob, woutT, out, 1024);
}

// Round 25
// 99.917 us; speedup vs baseline: 1.0283x; 1.0283x over previous
//
#include <hip/hip_runtime.h>

// Fused causal attention block: qkv = x@Wqkv -> flash-attn -> out = o@Wout
// B=2, S=2048, D=1024, H=16, hd=64. All matmuls in bf16 MFMA (fp32 accum).
// FINAL converged config (best measured 99.89-100.70 us over 5 runs):
//   prep_kernel  : fused x->bf16 + both weight transposes (HBM-bound, ~81% peak)
//   gemm_qkv     : 128x128/BK=64, 8 waves, XCD-chunked, bf16 A (pre-compressed:
//                  fp32-A fusion attempt cost +35 MB HBM re-fetch, reverted)
//   attn_kernel  : 4 waves/block, 4-way kv split, backfill; no-max softmax,
//                  swapped QK^T, in-register P repack (cvt_pk+permlane32_swap)
//   gemm_bt64    : 64x128 out-projection (2 blk/CU occupancy fix)

typedef unsigned short u16;
typedef unsigned int   u32;
typedef __attribute__((ext_vector_type(4))) u16    u16x4;
typedef __attribute__((ext_vector_type(8))) u16    u16x8;
typedef __attribute__((ext_vector_type(4))) short  s16x4;
typedef __attribute__((ext_vector_type(8))) __bf16 bf16x8;
typedef __attribute__((ext_vector_type(4))) float  f32x4;
typedef __attribute__((ext_vector_type(16))) float f32x16;

#define DEV static __device__ __forceinline__

DEV u16 f2b(float f) {             // fp32 -> bf16, round-to-nearest-even
  unsigned u = __float_as_uint(f);
  u += 0x7fffu + ((u >> 16) & 1u);
  return (u16)(u >> 16);
}

DEV void gload_lds16(const void* g, void* l) {
  __builtin_amdgcn_global_load_lds((const __attribute__((address_space(1))) void*)g,
                                   (__attribute__((address_space(3))) void*)l, 16, 0, 0);
}

DEV unsigned lds_off(const void* p) {
  return (unsigned)(unsigned long long)(const __attribute__((address_space(3))) void*)p;
}

// ds_read_b64_tr_b16: lane's byte addr A selects column (A>>3)&15 of the
// 128B-aligned 4x16 bf16 subtile containing A; returns elems col+16j, j=0..3.
DEV s16x4 tr_read(unsigned off) {
  s16x4 d;
  asm volatile("ds_read_b64_tr_b16 %0, %1" : "=v"(d) : "v"(off));
  return d;
}

DEV u32 cvt_pk(float lo, float hi) {   // packed {bf16(lo), bf16(hi)}
  u32 r;
  asm("v_cvt_pk_bf16_f32 %0, %1, %2" : "=v"(r) : "v"(lo), "v"(hi));
  return r;
}

// v_permlane32_swap_b32: x <- [x.lo31 | y.lo31], y <- [x.hi31 | y.hi31]
DEV void pswap(u32& x, u32& y) {
  asm volatile("v_permlane32_swap_b32 %0, %1" : "+v"(x), "+v"(y));
}

DEV f32x4 mfma32(bf16x8 a, bf16x8 b, f32x4 c) {
  return __builtin_amdgcn_mfma_f32_16x16x32_bf16(a, b, c, 0, 0, 0);
}
DEV f32x16 mfma3232(bf16x8 a, bf16x8 b, f32x16 c) {
  return __builtin_amdgcn_mfma_f32_32x32x16_bf16(a, b, c, 0, 0, 0);
}

// ------- fused prep: x->bf16 (blocks 0..4095), w_qkv^T (4096..7167, scaled
// first 1024 cols = W_q by 0.125*log2e), w_out^T (7168..8191). -------
__global__ __launch_bounds__(256) void prep_kernel(const float* __restrict__ x,
                                                   u16* __restrict__ xb,
                                                   const float* __restrict__ w_qkv,
                                                   u16* __restrict__ wqkvT,
                                                   const float* __restrict__ w_out,
                                                   u16* __restrict__ woutT) {
  __shared__ u16 ls[32][33];
  const int bid = (int)blockIdx.x;
  const int t = threadIdx.x;
  if (bid < 4096) {                       // ---- cvt: 4096*256*4 = 4M elems
    const int i = bid * 256 + t;
    const float4 v = ((const float4*)x)[i];
    u16x4 o = { f2b(v.x), f2b(v.y), f2b(v.z), f2b(v.w) };
    ((u16x4*)xb)[i] = o;
    return;
  }
  const float* w; u16* wt; int Ndim, tn, tk; float s;
  if (bid < 7168) {                       // ---- w_qkv [1024][3072] -> [3072][1024]
    const int q = bid - 4096;
    w = w_qkv; wt = wqkvT; Ndim = 3072;
    tn = (q % 96) * 32; tk = (q / 96) * 32;
    s = (tn < 1024) ? 0.18033688011112042f : 1.0f;   // scale W_q
  } else {                                // ---- w_out [1024][1024] -> [1024][1024]
    const int q = bid - 7168;
    w = w_out; wt = woutT; Ndim = 1024;
    tn = (q % 32) * 32; tk = (q / 32) * 32;
    s = 1.0f;
  }
  const int r = t >> 3, c4 = (t & 7) * 4;
  const float4 v = *(const float4*)(w + (size_t)(tk + r) * Ndim + tn + c4);
  ls[r][c4 + 0] = f2b(v.x * s); ls[r][c4 + 1] = f2b(v.y * s);
  ls[r][c4 + 2] = f2b(v.z * s); ls[r][c4 + 3] = f2b(v.w * s);
  __syncthreads();
  u16x4 ov = { ls[c4 + 0][r], ls[c4 + 1][r], ls[c4 + 2][r], ls[c4 + 3][r] };
  *(u16x4*)(wt + (size_t)(tn + r) * 1024 + tk + c4) = ov;
}

// ------- qkv GEMM: C[4096,3072](bf16) = A[4096,1024] @ Bt[3072,1024]^T -------
// 128x128 tile, BK=64, XCD-chunked swizzle, 8 WAVES (512 thr, 2M x 4N,
// wave-tile 64x32) for latency-hiding TLP through the 16 barrier cycles.
__global__ __launch_bounds__(512, 2) void gemm_qkv(const u16* __restrict__ A,
                                                   const u16* __restrict__ Bt,
                                                   u16* __restrict__ C, const int ldc) {
  const int gx = gridDim.x;
  const int id = (int)(blockIdx.y * gx + blockIdx.x);
  const int nxp = gx >> 3;                 // N-tiles per XCD chunk
  const int xcd = id & 7, loc = id >> 3;   // HW: XCD = id % 8 round-robin
  const int tn = (xcd * nxp + loc % nxp) * 128;
  const int tm = (loc / nxp) * 128;
  const int tid = (int)threadIdx.x;
  const int lane = tid & 63, wid = tid >> 6;
  const int wm = wid >> 2, wn = wid & 3;   // 2M x 4N waves
  const int lg = lane >> 4, lc = lane & 15;
  __shared__ __align__(128) u16 lsA[128 * 64];   // 16KB
  __shared__ __align__(128) u16 lsB[128 * 64];   // 16KB

  f32x4 acc[4][2];
#pragma unroll
  for (int i = 0; i < 4; ++i)
#pragma unroll
    for (int j = 0; j < 2; ++j) acc[i][j] = (f32x4){0.f, 0.f, 0.f, 0.f};

  for (int kt = 0; kt < 16; ++kt) {        // K-step = 64
#pragma unroll
    for (int c = 0; c < 2; ++c) {
      const int p = tid + c * 512;         // 1024 chunks per matrix
      const int row = p >> 3, ck = p & 7;
      const int cg = ck ^ (row & 7);       // inverse-swizzled source chunk
      gload_lds16(A  + (size_t)(tm + row) * 1024 + kt * 64 + cg * 8, (char*)lsA + p * 16);
      gload_lds16(Bt + (size_t)(tn + row) * 1024 + kt * 64 + cg * 8, (char*)lsB + p * 16);
    }
    __syncthreads();
#pragma unroll
    for (int kk = 0; kk < 2; ++kk) {       // two K=32 slices per K-step
      bf16x8 af[4], bg[2];
#pragma unroll
      for (int i = 0; i < 4; ++i) {
        const int ar = wm * 64 + i * 16 + lc;
        af[i] = *(const bf16x8*)(lsA + ar * 64 + ((kk * 4 + lg) ^ (ar & 7)) * 8);
      }
#pragma unroll
      for (int j = 0; j < 2; ++j) {
        const int br = wn * 32 + j * 16 + lc;
        bg[j] = *(const bf16x8*)(lsB + br * 64 + ((kk * 4 + lg) ^ (br & 7)) * 8);
      }
#pragma unroll
      for (int i = 0; i < 4; ++i)
#pragma unroll
        for (int j = 0; j < 2; ++j)
          acc[i][j] = mfma32(af[i], bg[j], acc[i][j]);
    }
    __syncthreads();
  }

#pragma unroll
  for (int i = 0; i < 4; ++i) {
#pragma unroll
    for (int r = 0; r < 4; ++r) {
      const int m = tm + wm * 64 + i * 16 + lg * 4 + r;   // C/D: row=(l>>4)*4+r
#pragma unroll
      for (int j = 0; j < 2; ++j) {
        const int n = tn + wn * 32 + j * 16 + lc;          // C/D: col=l&15
        C[(size_t)m * ldc + n] = f2b(acc[i][j][r]);
      }
    }
  }
}

// ------- 64x128-tile fp32-out GEMM for the out projection (occupancy fix) ---
__global__ __launch_bounds__(256) void gemm_bt64(const u16* __restrict__ A,
                                                 const u16* __restrict__ Bt,
                                                 float* __restrict__ C, const int ldc) {
  const int id = (int)(blockIdx.y * 8 + blockIdx.x);
  const int tn = (id & 7) * 128;
  const int tm = (id >> 3) * 64;
  const int tid = threadIdx.x;
  const int wave = tid >> 6, lane = tid & 63;
  const int wc = wave;                      // 4 waves = 4 n-quadrants of 32
  const int lg = lane >> 4, lc = lane & 15;
  __shared__ __align__(128) u16 lsA[64 * 32];    // 4KB
  __shared__ __align__(128) u16 lsB[128 * 32];   // 8KB

  f32x4 acc[4][2];
#pragma unroll
  for (int i = 0; i < 4; ++i)
#pragma unroll
    for (int j = 0; j < 2; ++j) acc[i][j] = (f32x4){0.f, 0.f, 0.f, 0.f};

  for (int kt = 0; kt < 32; ++kt) {
    {   // A: 256 chunks, 1 per thread
      const int p = tid;
      const int row = p >> 2, ck = p & 3;
      const int cg = ck ^ ((row >> 1) & 3);
      gload_lds16(A + (size_t)(tm + row) * 1024 + kt * 32 + cg * 8, (char*)lsA + p * 16);
    }
#pragma unroll
    for (int c = 0; c < 2; ++c) {   // B: 512 chunks, 2 per thread
      const int p = tid + c * 256;
      const int row = p >> 2, ck = p & 3;
      const int cg = ck ^ ((row >> 1) & 3);
      gload_lds16(Bt + (size_t)(tn + row) * 1024 + kt * 32 + cg * 8, (char*)lsB + p * 16);
    }
    __syncthreads();
    bf16x8 af[4], bg[2];
#pragma unroll
    for (int i = 0; i < 4; ++i) {
      const int ar = i * 16 + lc;
      af[i] = *(const bf16x8*)(lsA + ar * 32 + (lg ^ ((ar >> 1) & 3)) * 8);
    }
#pragma unroll
    for (int j = 0; j < 2; ++j) {
      const int br = wc * 32 + j * 16 + lc;
      bg[j] = *(const bf16x8*)(lsB + br * 32 + (lg ^ ((br >> 1) & 3)) * 8);
    }
#pragma unroll
    for (int i = 0; i < 4; ++i)
#pragma unroll
      for (int j = 0; j < 2; ++j)
        acc[i][j] = mfma32(af[i], bg[j], acc[i][j]);
    __syncthreads();
  }

#pragma unroll
  for (int i = 0; i < 4; ++i) {
#pragma unroll
    for (int r = 0; r < 4; ++r) {
      const int m = tm + i * 16 + lg * 4 + r;            // C/D: row=(l>>4)*4+r
#pragma unroll
      for (int j = 0; j < 2; ++j) {
        const int n = tn + wc * 32 + j * 16 + lc;        // C/D: col=l&15
        C[(size_t)m * ldc + n] = acc[i][j][r];
      }
    }
  }
}

// ------- flash attention v6: 4 waves/block, 4-way kv split, backfill -------
__global__ __launch_bounds__(256, 2) void attn_kernel(const u16* __restrict__ qkv,
                                                      u16* __restrict__ o) {
  const int qb  = 63 - (int)(blockIdx.x >> 5);  // LPT: longest first
  const int bh  = blockIdx.x & 31;
  const int b   = bh >> 4, h = bh & 15;
  const int tid  = threadIdx.x;
  const int wave = tid >> 6, lane = tid & 63;
  const int l31 = lane & 31, lg2 = lane >> 5;

  __shared__ __align__(128) char smem[4][8192];  // per-wave K(4KB)+V(4KB)
  __shared__ float lsm[4][32];
  char* wb = smem[wave];
  const unsigned vb = lds_off(wb + 4096);

  const size_t bS = (size_t)b * 2048;
  const int T  = qb + 1;
  const int q0 = qb * 32;

  const u16* qrow = qkv + (bS + q0 + l31) * 3072 + h * 64;
  bf16x8 qf[4];
#pragma unroll
  for (int m = 0; m < 4; ++m)
    qf[m] = *(const bf16x8*)(qrow + 16 * m + 8 * lg2);

  unsigned koff[4], voff[4];
#pragma unroll
  for (int c = 0; c < 4; ++c) {
    const int p = c * 64 + lane;
    {
      const int row = p >> 3;
      const int cg = (p & 7) ^ (row & 7);
      koff[c] = (unsigned)(row * 3072 + 1024 + h * 64 + cg * 8);
    }
    {
      const int s = p >> 3, cw = p & 7;
      voff[c] = (unsigned)((4 * (s >> 2) + (cw >> 1)) * 3072 + 2048 + h * 64
                           + (s & 3) * 16 + (cw & 1) * 8);
    }
  }

  auto STAGE = [&](int t) {
    const u16* base = qkv + (bS + (size_t)t * 32) * 3072;
#pragma unroll
    for (int c = 0; c < 4; ++c)
      gload_lds16(base + koff[c], wb + (c * 64 + lane) * 16);
#pragma unroll
    for (int c = 0; c < 4; ++c)
      gload_lds16(base + voff[c], wb + 4096 + (c * 64 + lane) * 16);
  };

  float lsum = 0.f;
  f32x16 accO[2];
#pragma unroll
  for (int r = 0; r < 16; ++r) { accO[0][r] = 0.f; accO[1][r] = 0.f; }

  if (wave < T) STAGE(wave);

  for (int t = wave; t < T; t += 4) {
    asm volatile("s_waitcnt vmcnt(0)" ::: "memory");   // own prefetch landed
    __builtin_amdgcn_sched_barrier(0);

    // ---- issue ALL DS reads of tile t up front ----
    const u16* kbp = (const u16*)wb + l31 * 64;
    bf16x8 kf[4];
#pragma unroll
    for (int m = 0; m < 4; ++m)
      kf[m] = *(const bf16x8*)(kbp + (((2 * m + lg2) ^ (l31 & 7)) * 8));
    s16x4 vr[2][2][2];
#pragma unroll
    for (int db = 0; db < 2; ++db)
#pragma unroll
      for (int hh = 0; hh < 2; ++hh) {
        const unsigned a0 = vb +
          (unsigned)(((4 * hh + 2 * lg2) * 4 + db * 2 + (l31 >> 4)) * 128 + (l31 & 15) * 8);
        vr[db][hh][0] = tr_read(a0);
        vr[db][hh][1] = tr_read(a0 + 512);
      }
    asm volatile("s_waitcnt lgkmcnt(0)" ::: "memory");  // buffer fully read out
    __builtin_amdgcn_sched_barrier(0);

    if (t + 4 < T) STAGE(t + 4);               // prefetch spans whole compute
    __builtin_amdgcn_sched_barrier(0);

    // ---- QK^T (A=K rows=kv=l31, B=Q cols=q) -> S[kv][q] ----
    f32x16 sc;
#pragma unroll
    for (int r = 0; r < 16; ++r) sc[r] = 0.f;
    __builtin_amdgcn_s_setprio(1);
#pragma unroll
    for (int m = 0; m < 4; ++m)
      sc = mfma3232(kf[m], qf[m], sc);
    __builtin_amdgcn_s_setprio(0);

    // ---- P = exp2(S) (scale folded into Q; no max-tracking) ----
    float pp[16];
    if (t == T - 1) {                          // diagonal tile: causal mask
#pragma unroll
      for (int r = 0; r < 16; ++r) {
        const int kvp = (r & 3) + 8 * (r >> 2) + 4 * lg2;
        pp[r] = (kvp <= l31) ? exp2f(sc[r]) : 0.f;
      }
    } else {
#pragma unroll
      for (int r = 0; r < 16; ++r) pp[r] = exp2f(sc[r]);
    }
#pragma unroll
    for (int r = 0; r < 16; ++r) lsum += pp[r];

    // ---- in-register P -> A-operand (8 cvt_pk + 4 permlane32_swap) ----
    u32 a01 = cvt_pk(pp[0], pp[1]),   a23 = cvt_pk(pp[2], pp[3]);
    u32 b01 = cvt_pk(pp[4], pp[5]),   b23 = cvt_pk(pp[6], pp[7]);
    u32 c01 = cvt_pk(pp[8], pp[9]),   c23 = cvt_pk(pp[10], pp[11]);
    u32 d01 = cvt_pk(pp[12], pp[13]), d23 = cvt_pk(pp[14], pp[15]);
    pswap(a01, b01); pswap(a23, b23);
    pswap(c01, d01); pswap(c23, d23);
    union Frag { u32 w[4]; bf16x8 v; };
    Frag f0, f1;
    f0.w[0] = a01; f0.w[1] = a23; f0.w[2] = b01; f0.w[3] = b23;
    f1.w[0] = c01; f1.w[1] = c23; f1.w[2] = d01; f1.w[3] = d23;

    // ---- PV: accO[dblk] += P * V ----
    __builtin_amdgcn_s_setprio(1);
#pragma unroll
    for (int db = 0; db < 2; ++db) {
      union { s16x4 hh[2]; bf16x8 v; } u0, u1;
      u0.hh[0] = vr[db][0][0]; u0.hh[1] = vr[db][0][1];
      u1.hh[0] = vr[db][1][0]; u1.hh[1] = vr[db][1][1];
      accO[db] = mfma3232(f0.v, u0.v, accO[db]);
      accO[db] = mfma3232(f1.v, u1.v, accO[db]);
    }
    __builtin_amdgcn_s_setprio(0);
  }

  // ---- merge: pairwise tree. regions A = smem[0], B = smem[2] (8KB each) ----
  lsum += __shfl_xor(lsum, 32);
  if (lane < 32) lsm[wave][l31] = lsum;
  float* mA = (float*)smem[0];                 // [32][64] f32
  float* mB = (float*)smem[2];                 // [32][64] f32
  __syncthreads();                             // all waves done with K/V LDS
  if ((wave & 1) == 0) {                       // w0 -> A, w2 -> B: write
    float* m = (wave == 0) ? mA : mB;
#pragma unroll
    for (int db = 0; db < 2; ++db)
#pragma unroll
      for (int r = 0; r < 16; ++r) {
        const int qp = (r & 3) + 8 * (r >> 2) + 4 * lg2;
        m[qp * 64 + db * 32 + l31] = accO[db][r];
      }
  }
  __syncthreads();
  if ((wave & 1) == 1) {                       // w1 -> A, w3 -> B: accumulate
    float* m = (wave == 1) ? mA : mB;
#pragma unroll
    for (int db = 0; db < 2; ++db)
#pragma unroll
      for (int r = 0; r < 16; ++r) {
        const int qp = (r & 3) + 8 * (r >> 2) + 4 * lg2;
        m[qp * 64 + db * 32 + l31] += accO[db][r];
      }
  }
  __syncthreads();

  // ---- epilogue: 256 threads, row q = tid>>3, cols d0..d0+7 ----
  const int q  = tid >> 3;
  const int d0 = (tid & 7) * 8;
  const float inv = 1.f / (lsm[0][q] + lsm[1][q] + lsm[2][q] + lsm[3][q]);
  u16x8 ov;
#pragma unroll
  for (int e = 0; e < 8; ++e)
    ov[e] = f2b((mA[q * 64 + d0 + e] + mB[q * 64 + d0 + e]) * inv);
  *(u16x8*)(o + (bS + q0 + q) * 1024 + h * 64 + d0) = ov;
}

// ---------------- launch ----------------
extern "C" void kernel_launch(void* const* d_in, const int* in_sizes, int n_in,
                              void* d_out, int out_size, void* d_ws, size_t ws_size,
                              hipStream_t stream) {
  const float* x     = (const float*)d_in[0];
  const float* w_qkv = (const float*)d_in[1];
  const float* w_out = (const float*)d_in[2];
  float* out = (float*)d_out;
  char* ws = (char*)d_ws;

  u16* xb    = (u16*)(ws + 0);          //  8.0 MB  x as bf16 [4096][1024]
  u16* wqkvT = (u16*)(ws + 8388608);    //  6.0 MB  w_qkv^T bf16 [3072][1024]
  u16* woutT = (u16*)(ws + 14680064);   //  2.0 MB  w_out^T bf16 [1024][1024]
  u16* qkvb  = (u16*)(ws + 16777216);   // 24.0 MB  qkv bf16 [4096][3072]
  u16* ob    = (u16*)(ws + 41943040);   //  8.0 MB  attn out bf16 [4096][1024]

  prep_kernel<<<8192, 256, 0, stream>>>(x, xb, w_qkv, wqkvT, w_out, woutT);
  gemm_qkv<<<dim3(24, 32), 512, 0, stream>>>(xb, wqkvT, qkvb, 3072);
  attn_kernel<<<2048, 256, 0, stream>>>(qkvb, ob);
  gemm_bt64<<<dim3(8, 64), 256, 0, stream>>>(ob, woutT, out, 1024);
}

// Round 26
// 99.835 us; speedup vs baseline: 1.0292x; 1.0008x over previous
//
#include <hip/hip_runtime.h>

// Fused causal attention block: qkv = x@Wqkv -> flash-attn -> out = o@Wout
// B=2, S=2048, D=1024, H=16, hd=64. All matmuls in bf16 MFMA (fp32 accum).
// FINAL converged config (measured 99.89-100.70 us over 6 runs):
//   prep_kernel  : fused x->bf16 + both weight transposes (HBM-bound, ~81% peak)
//   gemm_qkv     : 128x128/BK=64, 8 waves, XCD-chunked, bf16 A pre-compressed
//   attn_kernel  : 4 waves/block, 4-way kv split, backfill; no-max softmax,
//                  swapped QK^T, in-register P repack (cvt_pk+permlane32_swap)
//   gemm_bt64    : 64x128 out-projection (2 blk/CU occupancy fix)

typedef unsigned short u16;
typedef unsigned int   u32;
typedef __attribute__((ext_vector_type(4))) u16    u16x4;
typedef __attribute__((ext_vector_type(8))) u16    u16x8;
typedef __attribute__((ext_vector_type(4))) short  s16x4;
typedef __attribute__((ext_vector_type(8))) __bf16 bf16x8;
typedef __attribute__((ext_vector_type(4))) float  f32x4;
typedef __attribute__((ext_vector_type(16))) float f32x16;

#define DEV static __device__ __forceinline__

DEV u16 f2b(float f) {             // fp32 -> bf16, round-to-nearest-even
  unsigned u = __float_as_uint(f);
  u += 0x7fffu + ((u >> 16) & 1u);
  return (u16)(u >> 16);
}

DEV void gload_lds16(const void* g, void* l) {
  __builtin_amdgcn_global_load_lds((const __attribute__((address_space(1))) void*)g,
                                   (__attribute__((address_space(3))) void*)l, 16, 0, 0);
}

DEV unsigned lds_off(const void* p) {
  return (unsigned)(unsigned long long)(const __attribute__((address_space(3))) void*)p;
}

// ds_read_b64_tr_b16: lane's byte addr A selects column (A>>3)&15 of the
// 128B-aligned 4x16 bf16 subtile containing A; returns elems col+16j, j=0..3.
DEV s16x4 tr_read(unsigned off) {
  s16x4 d;
  asm volatile("ds_read_b64_tr_b16 %0, %1" : "=v"(d) : "v"(off));
  return d;
}

DEV u32 cvt_pk(float lo, float hi) {   // packed {bf16(lo), bf16(hi)}
  u32 r;
  asm("v_cvt_pk_bf16_f32 %0, %1, %2" : "=v"(r) : "v"(lo), "v"(hi));
  return r;
}

// v_permlane32_swap_b32: x <- [x.lo31 | y.lo31], y <- [x.hi31 | y.hi31]
DEV void pswap(u32& x, u32& y) {
  asm volatile("v_permlane32_swap_b32 %0, %1" : "+v"(x), "+v"(y));
}

DEV f32x4 mfma32(bf16x8 a, bf16x8 b, f32x4 c) {
  return __builtin_amdgcn_mfma_f32_16x16x32_bf16(a, b, c, 0, 0, 0);
}
DEV f32x16 mfma3232(bf16x8 a, bf16x8 b, f32x16 c) {
  return __builtin_amdgcn_mfma_f32_32x32x16_bf16(a, b, c, 0, 0, 0);
}

// ------- fused prep: x->bf16 (blocks 0..4095), w_qkv^T (4096..7167, scaled
// first 1024 cols = W_q by 0.125*log2e), w_out^T (7168..8191). -------
__global__ __launch_bounds__(256) void prep_kernel(const float* __restrict__ x,
                                                   u16* __restrict__ xb,
                                                   const float* __restrict__ w_qkv,
                                                   u16* __restrict__ wqkvT,
                                                   const float* __restrict__ w_out,
                                                   u16* __restrict__ woutT) {
  __shared__ u16 ls[32][33];
  const int bid = (int)blockIdx.x;
  const int t = threadIdx.x;
  if (bid < 4096) {                       // ---- cvt: 4096*256*4 = 4M elems
    const int i = bid * 256 + t;
    const float4 v = ((const float4*)x)[i];
    u16x4 o = { f2b(v.x), f2b(v.y), f2b(v.z), f2b(v.w) };
    ((u16x4*)xb)[i] = o;
    return;
  }
  const float* w; u16* wt; int Ndim, tn, tk; float s;
  if (bid < 7168) {                       // ---- w_qkv [1024][3072] -> [3072][1024]
    const int q = bid - 4096;
    w = w_qkv; wt = wqkvT; Ndim = 3072;
    tn = (q % 96) * 32; tk = (q / 96) * 32;
    s = (tn < 1024) ? 0.18033688011112042f : 1.0f;   // scale W_q
  } else {                                // ---- w_out [1024][1024] -> [1024][1024]
    const int q = bid - 7168;
    w = w_out; wt = woutT; Ndim = 1024;
    tn = (q % 32) * 32; tk = (q / 32) * 32;
    s = 1.0f;
  }
  const int r = t >> 3, c4 = (t & 7) * 4;
  const float4 v = *(const float4*)(w + (size_t)(tk + r) * Ndim + tn + c4);
  ls[r][c4 + 0] = f2b(v.x * s); ls[r][c4 + 1] = f2b(v.y * s);
  ls[r][c4 + 2] = f2b(v.z * s); ls[r][c4 + 3] = f2b(v.w * s);
  __syncthreads();
  u16x4 ov = { ls[c4 + 0][r], ls[c4 + 1][r], ls[c4 + 2][r], ls[c4 + 3][r] };
  *(u16x4*)(wt + (size_t)(tn + r) * 1024 + tk + c4) = ov;
}

// ------- qkv GEMM: C[4096,3072](bf16) = A[4096,1024] @ Bt[3072,1024]^T -------
// 128x128 tile, BK=64, XCD-chunked swizzle, 8 WAVES (512 thr, 2M x 4N,
// wave-tile 64x32) for latency-hiding TLP through the 16 barrier cycles.
__global__ __launch_bounds__(512, 2) void gemm_qkv(const u16* __restrict__ A,
                                                   const u16* __restrict__ Bt,
                                                   u16* __restrict__ C, const int ldc) {
  const int gx = gridDim.x;
  const int id = (int)(blockIdx.y * gx + blockIdx.x);
  const int nxp = gx >> 3;                 // N-tiles per XCD chunk
  const int xcd = id & 7, loc = id >> 3;   // HW: XCD = id % 8 round-robin
  const int tn = (xcd * nxp + loc % nxp) * 128;
  const int tm = (loc / nxp) * 128;
  const int tid = (int)threadIdx.x;
  const int lane = tid & 63, wid = tid >> 6;
  const int wm = wid >> 2, wn = wid & 3;   // 2M x 4N waves
  const int lg = lane >> 4, lc = lane & 15;
  __shared__ __align__(128) u16 lsA[128 * 64];   // 16KB
  __shared__ __align__(128) u16 lsB[128 * 64];   // 16KB

  f32x4 acc[4][2];
#pragma unroll
  for (int i = 0; i < 4; ++i)
#pragma unroll
    for (int j = 0; j < 2; ++j) acc[i][j] = (f32x4){0.f, 0.f, 0.f, 0.f};

  for (int kt = 0; kt < 16; ++kt) {        // K-step = 64
#pragma unroll
    for (int c = 0; c < 2; ++c) {
      const int p = tid + c * 512;         // 1024 chunks per matrix
      const int row = p >> 3, ck = p & 7;
      const int cg = ck ^ (row & 7);       // inverse-swizzled source chunk
      gload_lds16(A  + (size_t)(tm + row) * 1024 + kt * 64 + cg * 8, (char*)lsA + p * 16);
      gload_lds16(Bt + (size_t)(tn + row) * 1024 + kt * 64 + cg * 8, (char*)lsB + p * 16);
    }
    __syncthreads();
#pragma unroll
    for (int kk = 0; kk < 2; ++kk) {       // two K=32 slices per K-step
      bf16x8 af[4], bg[2];
#pragma unroll
      for (int i = 0; i < 4; ++i) {
        const int ar = wm * 64 + i * 16 + lc;
        af[i] = *(const bf16x8*)(lsA + ar * 64 + ((kk * 4 + lg) ^ (ar & 7)) * 8);
      }
#pragma unroll
      for (int j = 0; j < 2; ++j) {
        const int br = wn * 32 + j * 16 + lc;
        bg[j] = *(const bf16x8*)(lsB + br * 64 + ((kk * 4 + lg) ^ (br & 7)) * 8);
      }
#pragma unroll
      for (int i = 0; i < 4; ++i)
#pragma unroll
        for (int j = 0; j < 2; ++j)
          acc[i][j] = mfma32(af[i], bg[j], acc[i][j]);
    }
    __syncthreads();
  }

#pragma unroll
  for (int i = 0; i < 4; ++i) {
#pragma unroll
    for (int r = 0; r < 4; ++r) {
      const int m = tm + wm * 64 + i * 16 + lg * 4 + r;   // C/D: row=(l>>4)*4+r
#pragma unroll
      for (int j = 0; j < 2; ++j) {
        const int n = tn + wn * 32 + j * 16 + lc;          // C/D: col=l&15
        C[(size_t)m * ldc + n] = f2b(acc[i][j][r]);
      }
    }
  }
}

// ------- 64x128-tile fp32-out GEMM for the out projection (occupancy fix) ---
__global__ __launch_bounds__(256) void gemm_bt64(const u16* __restrict__ A,
                                                 const u16* __restrict__ Bt,
                                                 float* __restrict__ C, const int ldc) {
  const int id = (int)(blockIdx.y * 8 + blockIdx.x);
  const int tn = (id & 7) * 128;
  const int tm = (id >> 3) * 64;
  const int tid = threadIdx.x;
  const int wave = tid >> 6, lane = tid & 63;
  const int wc = wave;                      // 4 waves = 4 n-quadrants of 32
  const int lg = lane >> 4, lc = lane & 15;
  __shared__ __align__(128) u16 lsA[64 * 32];    // 4KB
  __shared__ __align__(128) u16 lsB[128 * 32];   // 8KB

  f32x4 acc[4][2];
#pragma unroll
  for (int i = 0; i < 4; ++i)
#pragma unroll
    for (int j = 0; j < 2; ++j) acc[i][j] = (f32x4){0.f, 0.f, 0.f, 0.f};

  for (int kt = 0; kt < 32; ++kt) {
    {   // A: 256 chunks, 1 per thread
      const int p = tid;
      const int row = p >> 2, ck = p & 3;
      const int cg = ck ^ ((row >> 1) & 3);
      gload_lds16(A + (size_t)(tm + row) * 1024 + kt * 32 + cg * 8, (char*)lsA + p * 16);
    }
#pragma unroll
    for (int c = 0; c < 2; ++c) {   // B: 512 chunks, 2 per thread
      const int p = tid + c * 256;
      const int row = p >> 2, ck = p & 3;
      const int cg = ck ^ ((row >> 1) & 3);
      gload_lds16(Bt + (size_t)(tn + row) * 1024 + kt * 32 + cg * 8, (char*)lsB + p * 16);
    }
    __syncthreads();
    bf16x8 af[4], bg[2];
#pragma unroll
    for (int i = 0; i < 4; ++i) {
      const int ar = i * 16 + lc;
      af[i] = *(const bf16x8*)(lsA + ar * 32 + (lg ^ ((ar >> 1) & 3)) * 8);
    }
#pragma unroll
    for (int j = 0; j < 2; ++j) {
      const int br = wc * 32 + j * 16 + lc;
      bg[j] = *(const bf16x8*)(lsB + br * 32 + (lg ^ ((br >> 1) & 3)) * 8);
    }
#pragma unroll
    for (int i = 0; i < 4; ++i)
#pragma unroll
      for (int j = 0; j < 2; ++j)
        acc[i][j] = mfma32(af[i], bg[j], acc[i][j]);
    __syncthreads();
  }

#pragma unroll
  for (int i = 0; i < 4; ++i) {
#pragma unroll
    for (int r = 0; r < 4; ++r) {
      const int m = tm + i * 16 + lg * 4 + r;            // C/D: row=(l>>4)*4+r
#pragma unroll
      for (int j = 0; j < 2; ++j) {
        const int n = tn + wc * 32 + j * 16 + lc;        // C/D: col=l&15
        C[(size_t)m * ldc + n] = acc[i][j][r];
      }
    }
  }
}

// ------- flash attention v6: 4 waves/block, 4-way kv split, backfill -------
__global__ __launch_bounds__(256, 2) void attn_kernel(const u16* __restrict__ qkv,
                                                      u16* __restrict__ o) {
  const int qb  = 63 - (int)(blockIdx.x >> 5);  // LPT: longest first
  const int bh  = blockIdx.x & 31;
  const int b   = bh >> 4, h = bh & 15;
  const int tid  = threadIdx.x;
  const int wave = tid >> 6, lane = tid & 63;
  const int l31 = lane & 31, lg2 = lane >> 5;

  __shared__ __align__(128) char smem[4][8192];  // per-wave K(4KB)+V(4KB)
  __shared__ float lsm[4][32];
  char* wb = smem[wave];
  const unsigned vb = lds_off(wb + 4096);

  const size_t bS = (size_t)b * 2048;
  const int T  = qb + 1;
  const int q0 = qb * 32;

  const u16* qrow = qkv + (bS + q0 + l31) * 3072 + h * 64;
  bf16x8 qf[4];
#pragma unroll
  for (int m = 0; m < 4; ++m)
    qf[m] = *(const bf16x8*)(qrow + 16 * m + 8 * lg2);

  unsigned koff[4], voff[4];
#pragma unroll
  for (int c = 0; c < 4; ++c) {
    const int p = c * 64 + lane;
    {
      const int row = p >> 3;
      const int cg = (p & 7) ^ (row & 7);
      koff[c] = (unsigned)(row * 3072 + 1024 + h * 64 + cg * 8);
    }
    {
      const int s = p >> 3, cw = p & 7;
      voff[c] = (unsigned)((4 * (s >> 2) + (cw >> 1)) * 3072 + 2048 + h * 64
                           + (s & 3) * 16 + (cw & 1) * 8);
    }
  }

  auto STAGE = [&](int t) {
    const u16* base = qkv + (bS + (size_t)t * 32) * 3072;
#pragma unroll
    for (int c = 0; c < 4; ++c)
      gload_lds16(base + koff[c], wb + (c * 64 + lane) * 16);
#pragma unroll
    for (int c = 0; c < 4; ++c)
      gload_lds16(base + voff[c], wb + 4096 + (c * 64 + lane) * 16);
  };

  float lsum = 0.f;
  f32x16 accO[2];
#pragma unroll
  for (int r = 0; r < 16; ++r) { accO[0][r] = 0.f; accO[1][r] = 0.f; }

  if (wave < T) STAGE(wave);

  for (int t = wave; t < T; t += 4) {
    asm volatile("s_waitcnt vmcnt(0)" ::: "memory");   // own prefetch landed
    __builtin_amdgcn_sched_barrier(0);

    // ---- issue ALL DS reads of tile t up front ----
    const u16* kbp = (const u16*)wb + l31 * 64;
    bf16x8 kf[4];
#pragma unroll
    for (int m = 0; m < 4; ++m)
      kf[m] = *(const bf16x8*)(kbp + (((2 * m + lg2) ^ (l31 & 7)) * 8));
    s16x4 vr[2][2][2];
#pragma unroll
    for (int db = 0; db < 2; ++db)
#pragma unroll
      for (int hh = 0; hh < 2; ++hh) {
        const unsigned a0 = vb +
          (unsigned)(((4 * hh + 2 * lg2) * 4 + db * 2 + (l31 >> 4)) * 128 + (l31 & 15) * 8);
        vr[db][hh][0] = tr_read(a0);
        vr[db][hh][1] = tr_read(a0 + 512);
      }
    asm volatile("s_waitcnt lgkmcnt(0)" ::: "memory");  // buffer fully read out
    __builtin_amdgcn_sched_barrier(0);

    if (t + 4 < T) STAGE(t + 4);               // prefetch spans whole compute
    __builtin_amdgcn_sched_barrier(0);

    // ---- QK^T (A=K rows=kv=l31, B=Q cols=q) -> S[kv][q] ----
    f32x16 sc;
#pragma unroll
    for (int r = 0; r < 16; ++r) sc[r] = 0.f;
    __builtin_amdgcn_s_setprio(1);
#pragma unroll
    for (int m = 0; m < 4; ++m)
      sc = mfma3232(kf[m], qf[m], sc);
    __builtin_amdgcn_s_setprio(0);

    // ---- P = exp2(S) (scale folded into Q; no max-tracking) ----
    float pp[16];
    if (t == T - 1) {                          // diagonal tile: causal mask
#pragma unroll
      for (int r = 0; r < 16; ++r) {
        const int kvp = (r & 3) + 8 * (r >> 2) + 4 * lg2;
        pp[r] = (kvp <= l31) ? exp2f(sc[r]) : 0.f;
      }
    } else {
#pragma unroll
      for (int r = 0; r < 16; ++r) pp[r] = exp2f(sc[r]);
    }
#pragma unroll
    for (int r = 0; r < 16; ++r) lsum += pp[r];

    // ---- in-register P -> A-operand (8 cvt_pk + 4 permlane32_swap) ----
    u32 a01 = cvt_pk(pp[0], pp[1]),   a23 = cvt_pk(pp[2], pp[3]);
    u32 b01 = cvt_pk(pp[4], pp[5]),   b23 = cvt_pk(pp[6], pp[7]);
    u32 c01 = cvt_pk(pp[8], pp[9]),   c23 = cvt_pk(pp[10], pp[11]);
    u32 d01 = cvt_pk(pp[12], pp[13]), d23 = cvt_pk(pp[14], pp[15]);
    pswap(a01, b01); pswap(a23, b23);
    pswap(c01, d01); pswap(c23, d23);
    union Frag { u32 w[4]; bf16x8 v; };
    Frag f0, f1;
    f0.w[0] = a01; f0.w[1] = a23; f0.w[2] = b01; f0.w[3] = b23;
    f1.w[0] = c01; f1.w[1] = c23; f1.w[2] = d01; f1.w[3] = d23;

    // ---- PV: accO[dblk] += P * V ----
    __builtin_amdgcn_s_setprio(1);
#pragma unroll
    for (int db = 0; db < 2; ++db) {
      union { s16x4 hh[2]; bf16x8 v; } u0, u1;
      u0.hh[0] = vr[db][0][0]; u0.hh[1] = vr[db][0][1];
      u1.hh[0] = vr[db][1][0]; u1.hh[1] = vr[db][1][1];
      accO[db] = mfma3232(f0.v, u0.v, accO[db]);
      accO[db] = mfma3232(f1.v, u1.v, accO[db]);
    }
    __builtin_amdgcn_s_setprio(0);
  }

  // ---- merge: pairwise tree. regions A = smem[0], B = smem[2] (8KB each) ----
  lsum += __shfl_xor(lsum, 32);
  if (lane < 32) lsm[wave][l31] = lsum;
  float* mA = (float*)smem[0];                 // [32][64] f32
  float* mB = (float*)smem[2];                 // [32][64] f32
  __syncthreads();                             // all waves done with K/V LDS
  if ((wave & 1) == 0) {                       // w0 -> A, w2 -> B: write
    float* m = (wave == 0) ? mA : mB;
#pragma unroll
    for (int db = 0; db < 2; ++db)
#pragma unroll
      for (int r = 0; r < 16; ++r) {
        const int qp = (r & 3) + 8 * (r >> 2) + 4 * lg2;
        m[qp * 64 + db * 32 + l31] = accO[db][r];
      }
  }
  __syncthreads();
  if ((wave & 1) == 1) {                       // w1 -> A, w3 -> B: accumulate
    float* m = (wave == 1) ? mA : mB;
#pragma unroll
    for (int db = 0; db < 2; ++db)
#pragma unroll
      for (int r = 0; r < 16; ++r) {
        const int qp = (r & 3) + 8 * (r >> 2) + 4 * lg2;
        m[qp * 64 + db * 32 + l31] += accO[db][r];
      }
  }
  __syncthreads();

  // ---- epilogue: 256 threads, row q = tid>>3, cols d0..d0+7 ----
  const int q  = tid >> 3;
  const int d0 = (tid & 7) * 8;
  const float inv = 1.f / (lsm[0][q] + lsm[1][q] + lsm[2][q] + lsm[3][q]);
  u16x8 ov;
#pragma unroll
  for (int e = 0; e < 8; ++e)
    ov[e] = f2b((mA[q * 64 + d0 + e] + mB[q * 64 + d0 + e]) * inv);
  *(u16x8*)(o + (bS + q0 + q) * 1024 + h * 64 + d0) = ov;
}

// ---------------- launch ----------------
extern "C" void kernel_launch(void* const* d_in, const int* in_sizes, int n_in,
                              void* d_out, int out_size, void* d_ws, size_t ws_size,
                              hipStream_t stream) {
  const float* x     = (const float*)d_in[0];
  const float* w_qkv = (const float*)d_in[1];
  const float* w_out = (const float*)d_in[2];
  float* out = (float*)d_out;
  char* ws = (char*)d_ws;

  u16* xb    = (u16*)(ws + 0);          //  8.0 MB  x as bf16 [4096][1024]
  u16* wqkvT = (u16*)(ws + 8388608);    //  6.0 MB  w_qkv^T bf16 [3072][1024]
  u16* woutT = (u16*)(ws + 14680064);   //  2.0 MB  w_out^T bf16 [1024][1024]
  u16* qkvb  = (u16*)(ws + 16777216);   // 24.0 MB  qkv bf16 [4096][3072]
  u16* ob    = (u16*)(ws + 41943040);   //  8.0 MB  attn out bf16 [4096][1024]

  prep_kernel<<<8192, 256, 0, stream>>>(x, xb, w_qkv, wqkvT, w_out, woutT);
  gemm_qkv<<<dim3(24, 32), 512, 0, stream>>>(xb, wqkvT, qkvb, 3072);
  attn_kernel<<<2048, 256, 0, stream>>>(qkvb, ob);
  gemm_bt64<<<dim3(8, 64), 256, 0, stream>>>(ob, woutT, out, 1024);
}